// Round 13
// baseline (618.191 us; speedup 1.0000x reference)
//
#include <hip/hip_runtime.h>
#include <math.h>

#define NNODES 100000
#define NEDGES 1600000
#define DIM 64
#define NGRAPHS 64
#define NEG_SLOPE 0.2f
#define SCAN_B 512
#define SCAN_NB ((NNODES + SCAN_B - 1) / SCAN_B)
#define MM_NB (NNODES / 16)                      // 6250 blocks for the fused mm0 part
#define SCATTER_NB ((NEDGES / 4 + 255) / 256)    // 1563 blocks, 4 edges/thread
#define WLT_S 68                                  // padded row stride (16B-aligned, bank-spread)

// ---------------- CSR construction (dst-sorted), self-loops excluded ----------------

__global__ void zero_kernel(int* __restrict__ counts, float* __restrict__ pooled) {
    int i = blockIdx.x * blockDim.x + threadIdx.x;
    if (i <= NNODES) counts[i] = 0;
    if (i < NGRAPHS * DIM) pooled[i] = 0.f;
}

// Histogram AND per-edge rank: atomicAdd's return value IS the edge's rank within
// its dst segment. Rank stored coalesced (int4); scatter pass needs no atomics.
__global__ void hist_kernel(const int4* __restrict__ src4, const int4* __restrict__ dst4,
                            int* __restrict__ counts, int4* __restrict__ rank4) {
    int e = blockIdx.x * blockDim.x + threadIdx.x;
    if (e < NEDGES / 4) {
        int4 s = src4[e], d = dst4[e];
        int4 r;
        r.x = (s.x != d.x) ? atomicAdd(&counts[d.x], 1) : 0;
        r.y = (s.y != d.y) ? atomicAdd(&counts[d.y], 1) : 0;
        r.z = (s.z != d.z) ? atomicAdd(&counts[d.z], 1) : 0;
        r.w = (s.w != d.w) ? atomicAdd(&counts[d.w], 1) : 0;
        rank4[e] = r;
    }
}

// In-place exclusive scan of counts -> per-block, plus block sums
__global__ void scan1_kernel(int* __restrict__ data, int* __restrict__ bsum) {
    __shared__ int tmp[SCAN_B];
    int t = threadIdx.x;
    int i = blockIdx.x * SCAN_B + t;
    int v = (i < NNODES) ? data[i] : 0;
    tmp[t] = v;
    __syncthreads();
    for (int off = 1; off < SCAN_B; off <<= 1) {
        int a = (t >= off) ? tmp[t - off] : 0;
        __syncthreads();
        if (t >= off) tmp[t] += a;
        __syncthreads();
    }
    if (i < NNODES) data[i] = tmp[t] - v;          // exclusive within block
    if (t == SCAN_B - 1) bsum[blockIdx.x] = tmp[t]; // block total
}

// One-block parallel exclusive scan of the SCAN_NB block sums (SCAN_NB <= 256)
__global__ void scan2_kernel(int* __restrict__ bsum, int* __restrict__ total) {
    __shared__ int tmp[256];
    int t = threadIdx.x;
    int v = (t < SCAN_NB) ? bsum[t] : 0;
    tmp[t] = v;
    __syncthreads();
    for (int off = 1; off < 256; off <<= 1) {
        int a = (t >= off) ? tmp[t - off] : 0;
        __syncthreads();
        if (t >= off) tmp[t] += a;
        __syncthreads();
    }
    if (t < SCAN_NB) bsum[t] = tmp[t] - v;  // exclusive
    if (t == 255) *total = tmp[t];
}

__global__ void scan3_kernel(int* __restrict__ offs, const int* __restrict__ bsum,
                             const int* __restrict__ total) {
    int i = blockIdx.x * SCAN_B + threadIdx.x;
    if (i < NNODES) offs[i] = offs[i] + bsum[blockIdx.x];
    if (i == 0) offs[NNODES] = *total;
}

// ---------------- FUSED: atomic-free CSR scatter + mm_alpha layer 0 -------------------
__global__ __launch_bounds__(256, 4) void scatter_mm_kernel(
        const int4* __restrict__ src4, const int4* __restrict__ dst4,
        const float4* __restrict__ eattr4, const int4* __restrict__ rank4,
        const int* __restrict__ offs, int2* __restrict__ csr,
        const float* __restrict__ hin, const float* __restrict__ W,
        const float* __restrict__ att,
        float* __restrict__ h2, float* __restrict__ ad, float* __restrict__ as_) {
    __shared__ float wl[DIM * DIM];
    __shared__ float hrow[4 * 4 * DIM];
    if (blockIdx.x < SCATTER_NB) {
        int e = blockIdx.x * 256 + threadIdx.x;
        if (e < NEDGES / 4) {
            int4 s = src4[e], d = dst4[e];
            int4 r = rank4[e];
            float4 v = eattr4[e];
            if (s.x != d.x) csr[offs[d.x] + r.x] = make_int2(s.x, __float_as_int(v.x));
            if (s.y != d.y) csr[offs[d.y] + r.y] = make_int2(s.y, __float_as_int(v.y));
            if (s.z != d.z) csr[offs[d.z] + r.z] = make_int2(s.z, __float_as_int(v.z));
            if (s.w != d.w) csr[offs[d.w] + r.w] = make_int2(s.w, __float_as_int(v.w));
        }
        return;   // block-uniform branch: no barrier divergence
    }
    int blk = blockIdx.x - SCATTER_NB;
    int t = threadIdx.x;
    for (int k = t; k < DIM * DIM; k += 256) wl[k] = W[k];
    __syncthreads();
    int lane = t & 63, w = t >> 6;
    float a0 = att[lane], a1 = att[DIM + lane];
    int rbase = blk * 16 + w * 4;
    float* hw = &hrow[w * 4 * DIM];
    #pragma unroll
    for (int r = 0; r < 4; ++r)
        hw[r * DIM + lane] = hin[(size_t)(rbase + r) * DIM + lane];
    float acc0 = 0.f, acc1 = 0.f, acc2 = 0.f, acc3 = 0.f;
    #pragma unroll 16
    for (int k = 0; k < DIM; ++k) {
        float wlk = wl[k * DIM + lane];
        acc0 = fmaf(hw[0 * DIM + k], wlk, acc0);
        acc1 = fmaf(hw[1 * DIM + k], wlk, acc1);
        acc2 = fmaf(hw[2 * DIM + k], wlk, acc2);
        acc3 = fmaf(hw[3 * DIM + k], wlk, acc3);
    }
    float accs[4] = {acc0, acc1, acc2, acc3};
    #pragma unroll
    for (int r = 0; r < 4; ++r) {
        int i = rbase + r;
        float acc = accs[r];
        h2[(size_t)i * DIM + lane] = acc;
        float vd = acc * a0, vs = acc * a1;
        #pragma unroll
        for (int off = 32; off; off >>= 1) {
            vd += __shfl_xor(vd, off, 64);
            vs += __shfl_xor(vs, off, 64);
        }
        if (lane == 0) { ad[i] = vd; as_[i] = vs; }
    }
}

// ---------------- Per-node GAT aggregation + FUSED next-layer matmul ------------------
// One wave per node. Logit phase: lane = edge (64-wide). Gather phase: quarter-wave
// per edge, 16 lanes x float4 = full row; 4 edges per global_load_dwordx4 issue.
// (s<<8, we) staged in LDS per 64-edge block (1 ds_read_b64 replaces 2 shfls).
__global__ __launch_bounds__(256) void gat_agg_kernel(
        const float* __restrict__ h2, const float* __restrict__ ad, const float* __restrict__ as_,
        const int* __restrict__ offs, const int2* __restrict__ csr,
        const float* __restrict__ att, const float* __restrict__ bias,
        const float* __restrict__ Wnext, const float* __restrict__ attNext,
        float* __restrict__ h2next, float* __restrict__ adNext, float* __restrict__ asNext,
        float* __restrict__ hout) {
    __shared__ float wlT[DIM * WLT_S];          // transposed W: wlT[c*WLT_S + k]
    __shared__ float hrow[4 * DIM];
    __shared__ int2  sw[4 * 64];                // per-wave (s<<8, we_bits) staging
    int t = threadIdx.x, lane = t & 63, w = t >> 6;
    if (Wnext) {                                // block-uniform: stage transposed W
        for (int idx = t; idx < DIM * DIM; idx += 256) {
            int k = idx >> 6, c = idx & 63;
            wlT[c * WLT_S + k] = Wnext[idx];
        }
        __syncthreads();
    }
    float a0n = 0.f, a1n = 0.f;
    if (Wnext) { a0n = attNext[lane]; a1n = attNext[DIM + lane]; }
    int q = lane >> 4, sl = lane & 15;
    int sl16 = sl * 16;                         // byte offset within a row
    int i = blockIdx.x * 4 + w;
    float att2 = att[2 * DIM];
    int beg = offs[i], end = offs[i + 1];
    float adi = ad[i];
    float ls = adi + as_[i];                    // self-loop logit (edge feature 0)
    ls = fmaxf(ls, NEG_SLOPE * ls);             // leaky relu
    float m = ls;
    float dsum = (lane == 0) ? 1.f : 0.f;       // self weight exp(ls-ls)=1, lane-partial
    float4 acc = make_float4(0.f, 0.f, 0.f, 0.f);
    if (q == 0)                                 // self contribution, weight 1
        acc = *(const float4*)((const char*)h2 + ((size_t)i << 8) + sl16);
    int2* swv = &sw[w * 64];
    for (int e0 = beg; e0 < end; e0 += 64) {
        int e = e0 + lane;
        float l = -INFINITY;
        int s = 0;
        if (e < end) {
            int2 sv = csr[e];                   // coalesced: contiguous per node
            s = sv.x;
            l = adi + as_[s] + __int_as_float(sv.y) * att2;
            l = fmaxf(l, NEG_SLOPE * l);
        }
        if (__any(l > m + 8.f)) {               // rare: rescale actually needed
            float bm = l;
            #pragma unroll
            for (int off = 32; off; off >>= 1) bm = fmaxf(bm, __shfl_xor(bm, off, 64));
            float sc = __expf(m - bm);
            dsum *= sc;
            acc.x *= sc; acc.y *= sc; acc.z *= sc; acc.w *= sc;
            m = bm;
        }
        float we = __expf(l - m);               // inactive lanes: exp(-inf) = 0
        dsum += we;
        swv[lane] = make_int2(s << 8, __float_as_int(we));  // same-wave RAW: ordered
        int cnt4 = (min(64, end - e0) + 3) >> 2;
        for (int j = 0; j < cnt4; ++j) {        // 4 edges per iteration (quarter-wave each)
            int2 p = swv[4 * j + q];            // broadcast to 16 lanes, conflict-free
            float wgt = __int_as_float(p.y);    // 0 for padded slots -> contributes 0
            float4 v = *(const float4*)((const char*)h2 + (size_t)(unsigned)p.x + sl16);
            acc.x = fmaf(wgt, v.x, acc.x);
            acc.y = fmaf(wgt, v.y, acc.y);
            acc.z = fmaf(wgt, v.z, acc.z);
            acc.w = fmaf(wgt, v.w, acc.w);
        }
    }
    // combine quarter-wave partial accumulators (xor-groups {l, l^16, l^32, l^48})
    #pragma unroll
    for (int off = 16; off <= 32; off <<= 1) {
        acc.x += __shfl_xor(acc.x, off, 64);
        acc.y += __shfl_xor(acc.y, off, 64);
        acc.z += __shfl_xor(acc.z, off, 64);
        acc.w += __shfl_xor(acc.w, off, 64);
    }
    #pragma unroll
    for (int off = 32; off; off >>= 1) dsum += __shfl_xor(dsum, off, 64);
    float4 bi = *(const float4*)&bias[sl * 4];
    float inv = 1.f / dsum;
    float4 o;
    o.x = fmaxf(fmaf(acc.x, inv, bi.x), 0.f);
    o.y = fmaxf(fmaf(acc.y, inv, bi.y), 0.f);
    o.z = fmaxf(fmaf(acc.z, inv, bi.z), 0.f);
    o.w = fmaxf(fmaf(acc.w, inv, bi.w), 0.f);
    if (!Wnext) {
        if (q == 0)
            *(float4*)((char*)hout + ((size_t)i << 8) + sl16) = o;
        return;
    }
    // Fused next-layer matmul: row i only -> per-node, no grid sync needed.
    if (q == 0)
        *(float4*)&hrow[w * DIM + sl * 4] = o;  // same-wave LDS RAW: ordered
    float h2v = 0.f;
    const float* wrow = &wlT[lane * WLT_S];
    const float* hr = &hrow[w * DIM];
    #pragma unroll
    for (int k = 0; k < DIM; k += 4) {
        float4 wv = *(const float4*)&wrow[k];   // per-lane row, padded stride
        float4 hv = *(const float4*)&hr[k];     // uniform addr: broadcast
        h2v = fmaf(hv.x, wv.x, h2v);
        h2v = fmaf(hv.y, wv.y, h2v);
        h2v = fmaf(hv.z, wv.z, h2v);
        h2v = fmaf(hv.w, wv.w, h2v);
    }
    h2next[(size_t)i * DIM + lane] = h2v;
    float vd = h2v * a0n, vs = h2v * a1n;
    #pragma unroll
    for (int off = 32; off; off >>= 1) {
        vd += __shfl_xor(vd, off, 64);
        vs += __shfl_xor(vs, off, 64);
    }
    if (lane == 0) { adNext[i] = vd; asNext[i] = vs; }
}

// ---------------- global_add_pool (batch is sorted) + final linear ----------------

__global__ __launch_bounds__(256) void pool_kernel(const float* __restrict__ h,
                                                   const int* __restrict__ batch,
                                                   float* __restrict__ pooled) {
    int t = threadIdx.x, lane = t & 63, w = t >> 6;
    int chunk = blockIdx.x * 4 + w;
    int i0 = chunk * 64;
    if (i0 >= NNODES) return;
    int iend = min(NNODES, i0 + 64);
    int cur = batch[i0];
    float acc = 0.f;
    for (int i = i0; i < iend; ++i) {
        int g = batch[i];                  // sorted: few transitions per chunk
        if (g != cur) { atomicAdd(&pooled[cur * DIM + lane], acc); acc = 0.f; cur = g; }
        acc += h[(size_t)i * DIM + lane];
    }
    atomicAdd(&pooled[cur * DIM + lane], acc);
}

__global__ void final_kernel(const float* __restrict__ pooled, const float* __restrict__ Wf,
                             const float* __restrict__ bf, float* __restrict__ out) {
    int t = threadIdx.x, lane = t & 63, w = t >> 6;
    for (int g = w; g < NGRAPHS; g += 4) {
        float v = pooled[g * DIM + lane] * Wf[lane];
        #pragma unroll
        for (int off = 32; off; off >>= 1) v += __shfl_xor(v, off, 64);
        if (lane == 0) out[g] = v + bf[0];
    }
}

// ---------------- launch ----------------

extern "C" void kernel_launch(void* const* d_in, const int* in_sizes, int n_in,
                              void* d_out, int out_size, void* d_ws, size_t ws_size,
                              hipStream_t stream) {
    const float* x      = (const float*)d_in[0];
    const int*   ei     = (const int*)d_in[1];
    const float* eattr  = (const float*)d_in[2];
    const int*   batch  = (const int*)d_in[3];
    const float* W[3]   = {(const float*)d_in[4], (const float*)d_in[7], (const float*)d_in[10]};
    const float* att[3] = {(const float*)d_in[5], (const float*)d_in[8], (const float*)d_in[11]};
    const float* bia[3] = {(const float*)d_in[6], (const float*)d_in[9], (const float*)d_in[12]};
    const float* Wf = (const float*)d_in[13];
    const float* bf = (const float*)d_in[14];
    float* out = (float*)d_out;
    const int* srcp = ei;            // edge_index row 0
    const int* dstp = ei + NEDGES;   // edge_index row 1

    char* p = (char*)d_ws;
    auto alloc = [&](size_t bytes) { char* r = p; p += (bytes + 255) & ~size_t(255); return r; };
    int*   offs    = (int*)alloc((NNODES + 1) * sizeof(int));
    int*   rank    = (int*)alloc((size_t)NEDGES * sizeof(int));
    int*   bsum    = (int*)alloc(SCAN_NB * sizeof(int));
    int*   total   = (int*)alloc(sizeof(int));
    int2*  csr     = (int2*)alloc((size_t)NEDGES * sizeof(int2));
    float* h2a     = (float*)alloc((size_t)NNODES * DIM * sizeof(float));
    float* ad_a    = (float*)alloc(NNODES * sizeof(float));
    float* as_a    = (float*)alloc(NNODES * sizeof(float));
    float* h2b     = (float*)alloc((size_t)NNODES * DIM * sizeof(float));
    float* ad_b    = (float*)alloc(NNODES * sizeof(float));
    float* as_b    = (float*)alloc(NNODES * sizeof(float));
    float* pooled  = (float*)alloc(NGRAPHS * DIM * sizeof(float));

    // CSR build (same work every call; edges are layer-invariant)
    zero_kernel<<<(NNODES + 256) / 256, 256, 0, stream>>>(offs, pooled);
    hist_kernel<<<(NEDGES / 4 + 255) / 256, 256, 0, stream>>>(
        (const int4*)srcp, (const int4*)dstp, offs, (int4*)rank);
    scan1_kernel<<<SCAN_NB, SCAN_B, 0, stream>>>(offs, bsum);
    scan2_kernel<<<1, 256, 0, stream>>>(bsum, total);
    scan3_kernel<<<SCAN_NB, SCAN_B, 0, stream>>>(offs, bsum, total);

    // Fused: atomic-free CSR scatter (dispatched first) + layer-0 matmul
    scatter_mm_kernel<<<SCATTER_NB + MM_NB, 256, 0, stream>>>(
        (const int4*)srcp, (const int4*)dstp, (const float4*)eattr, (const int4*)rank,
        offs, csr, x, W[0], att[0], h2a, ad_a, as_a);

    // agg0 (layer0) + fused mm1:  h2a -> h2b
    gat_agg_kernel<<<NNODES / 4, 256, 0, stream>>>(
        h2a, ad_a, as_a, offs, csr, att[0], bia[0],
        W[1], att[1], h2b, ad_b, as_b, (float*)nullptr);
    // agg1 (layer1) + fused mm2:  h2b -> h2a
    gat_agg_kernel<<<NNODES / 4, 256, 0, stream>>>(
        h2b, ad_b, as_b, offs, csr, att[1], bia[1],
        W[2], att[2], h2a, ad_a, as_a, (float*)nullptr);
    // agg2 (layer2, plain): h2a -> h2b (= final node features)
    gat_agg_kernel<<<NNODES / 4, 256, 0, stream>>>(
        h2a, ad_a, as_a, offs, csr, att[2], bia[2],
        (const float*)nullptr, (const float*)nullptr,
        (float*)nullptr, (float*)nullptr, (float*)nullptr, h2b);

    pool_kernel<<<(((NNODES + 63) / 64) + 3) / 4, 256, 0, stream>>>(h2b, batch, pooled);
    final_kernel<<<1, 256, 0, stream>>>(pooled, Wf, bf, out);
}

// Round 16
// 581.770 us; speedup vs baseline: 1.0626x; 1.0626x over previous
//
#include <hip/hip_runtime.h>
#include <hip/hip_fp16.h>
#include <math.h>

#define NNODES 100000
#define NEDGES 1600000
#define DIM 64
#define NGRAPHS 64
#define NEG_SLOPE 0.2f
#define SCAN_B 512
#define SCAN_NB ((NNODES + SCAN_B - 1) / SCAN_B)
#define MM_NB (NNODES / 16)                      // 6250 blocks for the fused mm0 part
#define SCATTER_NB ((NEDGES / 4 + 255) / 256)    // 1563 blocks, 4 edges/thread

// ---------------- CSR construction (dst-sorted), self-loops excluded ----------------

__global__ void zero_kernel(int* __restrict__ counts, float* __restrict__ pooled) {
    int i = blockIdx.x * blockDim.x + threadIdx.x;
    if (i <= NNODES) counts[i] = 0;
    if (i < NGRAPHS * DIM) pooled[i] = 0.f;
}

// Histogram AND per-edge rank: atomicAdd's return value IS the edge's rank within
// its dst segment. Rank stored coalesced (int4); scatter pass needs no atomics.
__global__ void hist_kernel(const int4* __restrict__ src4, const int4* __restrict__ dst4,
                            int* __restrict__ counts, int4* __restrict__ rank4) {
    int e = blockIdx.x * blockDim.x + threadIdx.x;
    if (e < NEDGES / 4) {
        int4 s = src4[e], d = dst4[e];
        int4 r;
        r.x = (s.x != d.x) ? atomicAdd(&counts[d.x], 1) : 0;
        r.y = (s.y != d.y) ? atomicAdd(&counts[d.y], 1) : 0;
        r.z = (s.z != d.z) ? atomicAdd(&counts[d.z], 1) : 0;
        r.w = (s.w != d.w) ? atomicAdd(&counts[d.w], 1) : 0;
        rank4[e] = r;
    }
}

// In-place exclusive scan of counts -> per-block, plus block sums
__global__ void scan1_kernel(int* __restrict__ data, int* __restrict__ bsum) {
    __shared__ int tmp[SCAN_B];
    int t = threadIdx.x;
    int i = blockIdx.x * SCAN_B + t;
    int v = (i < NNODES) ? data[i] : 0;
    tmp[t] = v;
    __syncthreads();
    for (int off = 1; off < SCAN_B; off <<= 1) {
        int a = (t >= off) ? tmp[t - off] : 0;
        __syncthreads();
        if (t >= off) tmp[t] += a;
        __syncthreads();
    }
    if (i < NNODES) data[i] = tmp[t] - v;          // exclusive within block
    if (t == SCAN_B - 1) bsum[blockIdx.x] = tmp[t]; // block total
}

// One-block parallel exclusive scan of the SCAN_NB block sums (SCAN_NB <= 256)
__global__ void scan2_kernel(int* __restrict__ bsum, int* __restrict__ total) {
    __shared__ int tmp[256];
    int t = threadIdx.x;
    int v = (t < SCAN_NB) ? bsum[t] : 0;
    tmp[t] = v;
    __syncthreads();
    for (int off = 1; off < 256; off <<= 1) {
        int a = (t >= off) ? tmp[t - off] : 0;
        __syncthreads();
        if (t >= off) tmp[t] += a;
        __syncthreads();
    }
    if (t < SCAN_NB) bsum[t] = tmp[t] - v;  // exclusive
    if (t == 255) *total = tmp[t];
}

__global__ void scan3_kernel(int* __restrict__ offs, const int* __restrict__ bsum,
                             const int* __restrict__ total) {
    int i = blockIdx.x * SCAN_B + threadIdx.x;
    if (i < NNODES) offs[i] = offs[i] + bsum[blockIdx.x];
    if (i == 0) offs[NNODES] = *total;
}

// ---------------- FUSED: atomic-free CSR scatter + mm_alpha layer 0 -------------------
// h2 table stored fp16 (gather bandwidth); ad/as computed from fp32 acc pre-rounding.
__global__ __launch_bounds__(256, 4) void scatter_mm_kernel(
        const int4* __restrict__ src4, const int4* __restrict__ dst4,
        const float4* __restrict__ eattr4, const int4* __restrict__ rank4,
        const int* __restrict__ offs, int2* __restrict__ csr,
        const float* __restrict__ hin, const float* __restrict__ W,
        const float* __restrict__ att,
        __half* __restrict__ h2, float* __restrict__ ad, float* __restrict__ as_) {
    __shared__ float wl[DIM * DIM];
    __shared__ float hrow[4 * 4 * DIM];
    if (blockIdx.x < SCATTER_NB) {
        int e = blockIdx.x * 256 + threadIdx.x;
        if (e < NEDGES / 4) {
            int4 s = src4[e], d = dst4[e];
            int4 r = rank4[e];
            float4 v = eattr4[e];
            if (s.x != d.x) csr[offs[d.x] + r.x] = make_int2(s.x, __float_as_int(v.x));
            if (s.y != d.y) csr[offs[d.y] + r.y] = make_int2(s.y, __float_as_int(v.y));
            if (s.z != d.z) csr[offs[d.z] + r.z] = make_int2(s.z, __float_as_int(v.z));
            if (s.w != d.w) csr[offs[d.w] + r.w] = make_int2(s.w, __float_as_int(v.w));
        }
        return;   // block-uniform branch: no barrier divergence
    }
    int blk = blockIdx.x - SCATTER_NB;
    int t = threadIdx.x;
    for (int k = t; k < DIM * DIM; k += 256) wl[k] = W[k];
    __syncthreads();
    int lane = t & 63, w = t >> 6;
    float a0 = att[lane], a1 = att[DIM + lane];
    int rbase = blk * 16 + w * 4;
    float* hw = &hrow[w * 4 * DIM];
    #pragma unroll
    for (int r = 0; r < 4; ++r)
        hw[r * DIM + lane] = hin[(size_t)(rbase + r) * DIM + lane];
    float acc0 = 0.f, acc1 = 0.f, acc2 = 0.f, acc3 = 0.f;
    #pragma unroll 16
    for (int k = 0; k < DIM; ++k) {
        float wlk = wl[k * DIM + lane];
        acc0 = fmaf(hw[0 * DIM + k], wlk, acc0);
        acc1 = fmaf(hw[1 * DIM + k], wlk, acc1);
        acc2 = fmaf(hw[2 * DIM + k], wlk, acc2);
        acc3 = fmaf(hw[3 * DIM + k], wlk, acc3);
    }
    float accs[4] = {acc0, acc1, acc2, acc3};
    #pragma unroll
    for (int r = 0; r < 4; ++r) {
        int i = rbase + r;
        float acc = accs[r];
        h2[(size_t)i * DIM + lane] = __float2half(acc);
        float vd = acc * a0, vs = acc * a1;
        #pragma unroll
        for (int off = 32; off; off >>= 1) {
            vd += __shfl_xor(vd, off, 64);
            vs += __shfl_xor(vs, off, 64);
        }
        if (lane == 0) { ad[i] = vd; as_[i] = vs; }
    }
}

// ---------------- Per-node GAT aggregation + FUSED next-layer matmul ------------------
// One wave per node; lane = channel. Online softmax with ballot fast-path. 8-deep
// double-buffered fp16 gathers (128B/edge). All arithmetic fp32; logits exact.
__global__ __launch_bounds__(256) void gat_agg_kernel(
        const __half* __restrict__ h2, const float* __restrict__ ad, const float* __restrict__ as_,
        const int* __restrict__ offs, const int2* __restrict__ csr,
        const float* __restrict__ att, const float* __restrict__ bias,
        const float* __restrict__ Wnext, const float* __restrict__ attNext,
        __half* __restrict__ h2next, float* __restrict__ adNext, float* __restrict__ asNext,
        float* __restrict__ hout) {
    __shared__ float wl[DIM * DIM];
    __shared__ float hrow[4 * DIM];
    int t = threadIdx.x, lane = t & 63, w = t >> 6;
    if (Wnext) {                                 // block-uniform: stage next-layer W
        for (int k = t; k < DIM * DIM; k += 256) wl[k] = Wnext[k];
        __syncthreads();
    }
    float a0n = 0.f, a1n = 0.f;
    if (Wnext) { a0n = attNext[lane]; a1n = attNext[DIM + lane]; }
    int i = blockIdx.x * 4 + w;
    float att2 = att[2 * DIM];
    int beg = offs[i], end = offs[i + 1];
    float adi = ad[i];
    float ls = adi + as_[i];                    // self-loop logit (edge feature 0)
    ls = fmaxf(ls, NEG_SLOPE * ls);
    float m = ls;
    float dsum = (lane == 0) ? 1.f : 0.f;       // self weight exp(ls-ls)=1, lane-partial
    float acc = __half2float(h2[(size_t)i * DIM + lane]);  // self contribution, weight 1
    for (int e0 = beg; e0 < end; e0 += 64) {
        int e = e0 + lane;
        float l = -INFINITY;
        int s = 0;
        if (e < end) {
            int2 sv = csr[e];                   // coalesced: contiguous per node
            s = sv.x;
            l = adi + as_[s] + __int_as_float(sv.y) * att2;
            l = fmaxf(l, NEG_SLOPE * l);
        }
        if (__any(l > m + 8.f)) {               // rare: rescale actually needed
            float bm = l;
            #pragma unroll
            for (int off = 32; off; off >>= 1) bm = fmaxf(bm, __shfl_xor(bm, off, 64));
            float sc = __expf(m - bm);
            dsum *= sc; acc *= sc; m = bm;
        }
        float we = __expf(l - m);               // inactive lanes: exp(-inf) = 0
        dsum += we;
        int cnt = min(64, end - e0);
        float va[8], vb[8];
        if (cnt >= 8) {                         // preload batch 0
            #pragma unroll
            for (int k = 0; k < 8; ++k) {
                int sj = __shfl(s, k, 64);
                va[k] = __half2float(h2[(size_t)sj * DIM + lane]);
            }
        }
        int j = 0;
        while (j + 8 <= cnt) {
            bool hasNext = (j + 16 <= cnt);
            if (hasNext) {                      // issue next batch BEFORE consuming
                #pragma unroll
                for (int k = 0; k < 8; ++k) {
                    int sj = __shfl(s, j + 8 + k, 64);
                    vb[k] = __half2float(h2[(size_t)sj * DIM + lane]);
                }
            }
            #pragma unroll
            for (int k = 0; k < 8; ++k) {
                float wgt = __shfl(we, j + k, 64);
                acc = fmaf(wgt, va[k], acc);
            }
            if (hasNext) {
                #pragma unroll
                for (int k = 0; k < 8; ++k) va[k] = vb[k];
            }
            j += 8;
        }
        for (; j < cnt; ++j) {                  // tail (< 8 edges)
            float wgt = __shfl(we, j, 64);
            int sj = __shfl(s, j, 64);
            acc = fmaf(wgt, __half2float(h2[(size_t)sj * DIM + lane]), acc);
        }
    }
    #pragma unroll
    for (int off = 32; off; off >>= 1) dsum += __shfl_xor(dsum, off, 64);
    float o = fmaxf(acc / dsum + bias[lane], 0.f);   // this layer's relu'd output
    if (!Wnext) {
        hout[(size_t)i * DIM + lane] = o;       // final layer: fp32 for pooling
        return;
    }
    // Fused next-layer matmul: row i only -> per-node, no grid sync needed.
    hrow[w * DIM + lane] = o;                   // same-wave LDS RAW: ordered
    float h2v = 0.f;
    #pragma unroll 8
    for (int k = 0; k < DIM; ++k)
        h2v = fmaf(hrow[w * DIM + k], wl[k * DIM + lane], h2v);
    h2next[(size_t)i * DIM + lane] = __float2half(h2v);
    float vd = h2v * a0n, vs = h2v * a1n;       // alpha dots from fp32 (exact logits)
    #pragma unroll
    for (int off = 32; off; off >>= 1) {
        vd += __shfl_xor(vd, off, 64);
        vs += __shfl_xor(vs, off, 64);
    }
    if (lane == 0) { adNext[i] = vd; asNext[i] = vs; }
}

// ---------------- global_add_pool (batch is sorted) + final linear ----------------

__global__ __launch_bounds__(256) void pool_kernel(const float* __restrict__ h,
                                                   const int* __restrict__ batch,
                                                   float* __restrict__ pooled) {
    int t = threadIdx.x, lane = t & 63, w = t >> 6;
    int chunk = blockIdx.x * 4 + w;
    int i0 = chunk * 64;
    if (i0 >= NNODES) return;
    int iend = min(NNODES, i0 + 64);
    int cur = batch[i0];
    float acc = 0.f;
    for (int i = i0; i < iend; ++i) {
        int g = batch[i];                  // sorted: few transitions per chunk
        if (g != cur) { atomicAdd(&pooled[cur * DIM + lane], acc); acc = 0.f; cur = g; }
        acc += h[(size_t)i * DIM + lane];
    }
    atomicAdd(&pooled[cur * DIM + lane], acc);
}

__global__ void final_kernel(const float* __restrict__ pooled, const float* __restrict__ Wf,
                             const float* __restrict__ bf, float* __restrict__ out) {
    int t = threadIdx.x, lane = t & 63, w = t >> 6;
    for (int g = w; g < NGRAPHS; g += 4) {
        float v = pooled[g * DIM + lane] * Wf[lane];
        #pragma unroll
        for (int off = 32; off; off >>= 1) v += __shfl_xor(v, off, 64);
        if (lane == 0) out[g] = v + bf[0];
    }
}

// ---------------- launch ----------------

extern "C" void kernel_launch(void* const* d_in, const int* in_sizes, int n_in,
                              void* d_out, int out_size, void* d_ws, size_t ws_size,
                              hipStream_t stream) {
    const float* x      = (const float*)d_in[0];
    const int*   ei     = (const int*)d_in[1];
    const float* eattr  = (const float*)d_in[2];
    const int*   batch  = (const int*)d_in[3];
    const float* W[3]   = {(const float*)d_in[4], (const float*)d_in[7], (const float*)d_in[10]};
    const float* att[3] = {(const float*)d_in[5], (const float*)d_in[8], (const float*)d_in[11]};
    const float* bia[3] = {(const float*)d_in[6], (const float*)d_in[9], (const float*)d_in[12]};
    const float* Wf = (const float*)d_in[13];
    const float* bf = (const float*)d_in[14];
    float* out = (float*)d_out;
    const int* srcp = ei;            // edge_index row 0
    const int* dstp = ei + NEDGES;   // edge_index row 1

    char* p = (char*)d_ws;
    auto alloc = [&](size_t bytes) { char* r = p; p += (bytes + 255) & ~size_t(255); return r; };
    int*    offs    = (int*)alloc((NNODES + 1) * sizeof(int));
    int*    rank    = (int*)alloc((size_t)NEDGES * sizeof(int));
    int*    bsum    = (int*)alloc(SCAN_NB * sizeof(int));
    int*    total   = (int*)alloc(sizeof(int));
    int2*   csr     = (int2*)alloc((size_t)NEDGES * sizeof(int2));
    __half* h2a     = (__half*)alloc((size_t)NNODES * DIM * sizeof(__half));
    float*  ad_a    = (float*)alloc(NNODES * sizeof(float));
    float*  as_a    = (float*)alloc(NNODES * sizeof(float));
    __half* h2b     = (__half*)alloc((size_t)NNODES * DIM * sizeof(__half));
    float*  ad_b    = (float*)alloc(NNODES * sizeof(float));
    float*  as_b    = (float*)alloc(NNODES * sizeof(float));
    float*  houtf   = (float*)alloc((size_t)NNODES * DIM * sizeof(float));
    float*  pooled  = (float*)alloc(NGRAPHS * DIM * sizeof(float));

    // CSR build (same work every call; edges are layer-invariant)
    zero_kernel<<<(NNODES + 256) / 256, 256, 0, stream>>>(offs, pooled);
    hist_kernel<<<(NEDGES / 4 + 255) / 256, 256, 0, stream>>>(
        (const int4*)srcp, (const int4*)dstp, offs, (int4*)rank);
    scan1_kernel<<<SCAN_NB, SCAN_B, 0, stream>>>(offs, bsum);
    scan2_kernel<<<1, 256, 0, stream>>>(bsum, total);
    scan3_kernel<<<SCAN_NB, SCAN_B, 0, stream>>>(offs, bsum, total);

    // Fused: atomic-free CSR scatter (dispatched first) + layer-0 matmul
    scatter_mm_kernel<<<SCATTER_NB + MM_NB, 256, 0, stream>>>(
        (const int4*)srcp, (const int4*)dstp, (const float4*)eattr, (const int4*)rank,
        offs, csr, x, W[0], att[0], h2a, ad_a, as_a);

    // agg0 (layer0) + fused mm1:  h2a -> h2b
    gat_agg_kernel<<<NNODES / 4, 256, 0, stream>>>(
        h2a, ad_a, as_a, offs, csr, att[0], bia[0],
        W[1], att[1], h2b, ad_b, as_b, (float*)nullptr);
    // agg1 (layer1) + fused mm2:  h2b -> h2a
    gat_agg_kernel<<<NNODES / 4, 256, 0, stream>>>(
        h2b, ad_b, as_b, offs, csr, att[1], bia[1],
        W[2], att[2], h2a, ad_a, as_a, (float*)nullptr);
    // agg2 (layer2, plain): h2a -> houtf (fp32 final node features)
    gat_agg_kernel<<<NNODES / 4, 256, 0, stream>>>(
        h2a, ad_a, as_a, offs, csr, att[2], bia[2],
        (const float*)nullptr, (const float*)nullptr,
        (__half*)nullptr, (float*)nullptr, (float*)nullptr, houtf);

    pool_kernel<<<(((NNODES + 63) / 64) + 3) / 4, 256, 0, stream>>>(houtf, batch, pooled);
    final_kernel<<<1, 256, 0, stream>>>(pooled, Wf, bf, out);
}